// Round 6
// baseline (379.347 us; speedup 1.0000x reference)
//
#include <hip/hip_runtime.h>
#include <hip/hip_bf16.h>

// KMeans assign via fp16 coarse MFMA + exact fp32 fixup of near-tie rows.
// argmin_k ||xe - c_k|| == argmin_k ( ||c_k||^2 - 2*xe.c_k ),  xe = x + 1e-6.
// R6: dist carries per-row top2 as PACKED sortable keys (value-quantized,
// idx in low 11 bits) -> 32 extra VGPRs (stays <=128 class, unlike R4's 48),
// butterfly once per block over 512 cols. csq recentred by -448 (Sterbenz-
// exact) so quant step <=0.0625; TAU inflated 0.3->0.45 to cover it.
// fixup retiled 32x128 for CU balance (~650 active blocks vs ~128).

#define EPS 1e-6f
#define TAUP 0.45f

constexpr int BROWS = 32768;   // 8*4096 rows
constexpr int DD    = 512;
constexpr int KC    = 2048;    // centroids
constexpr int FCAP  = 4096;    // max flagged rows handled exactly

typedef _Float16 half8  __attribute__((ext_vector_type(8)));
typedef float    f32x4  __attribute__((ext_vector_type(4)));

__device__ __forceinline__ unsigned sortable(float f) {
    unsigned s = __float_as_uint(f);
    return s ^ (unsigned)(((int)s >> 31) | 0x80000000);
}
__device__ __forceinline__ float unsortable(unsigned u) {
    unsigned s = (u & 0x80000000u) ? (u ^ 0x80000000u) : ~u;
    return __uint_as_float(s);
}

// ---------------- fused prep: x->fp16(+eps) | centroids->fp16 + csq ---------
__global__ __launch_bounds__(256) void prep(const float* __restrict__ x,
                                            const float* __restrict__ cen,
                                            _Float16* __restrict__ xh,
                                            _Float16* __restrict__ ch,
                                            float* __restrict__ csq,
                                            int* __restrict__ rlist,
                                            int* __restrict__ ctr) {
    int b = blockIdx.x;
    if (b < 8192) {                                  // x part: 8192 blocks
        size_t i = ((size_t)b * 256 + threadIdx.x) * 8;
        float4 v0 = *(const float4*)(x + i);
        float4 v1 = *(const float4*)(x + i + 4);
        half8 h;
        h[0] = (_Float16)(v0.x + EPS); h[1] = (_Float16)(v0.y + EPS);
        h[2] = (_Float16)(v0.z + EPS); h[3] = (_Float16)(v0.w + EPS);
        h[4] = (_Float16)(v1.x + EPS); h[5] = (_Float16)(v1.y + EPS);
        h[6] = (_Float16)(v1.z + EPS); h[7] = (_Float16)(v1.w + EPS);
        *(half8*)(xh + i) = h;
        if (b == 0 && threadIdx.x == 0) *ctr = 0;
    } else {                                         // centroid part: 512 blocks
        int cb = b - 8192;
        int w = threadIdx.x >> 6, lane = threadIdx.x & 63;
        int c = cb * 4 + w;                          // 0..2047
        const float* row = cen + (size_t)c * DD;
        float4 v0 = *(const float4*)(row + lane * 8);
        float4 v1 = *(const float4*)(row + lane * 8 + 4);
        half8 h;
        h[0] = (_Float16)v0.x; h[1] = (_Float16)v0.y; h[2] = (_Float16)v0.z; h[3] = (_Float16)v0.w;
        h[4] = (_Float16)v1.x; h[5] = (_Float16)v1.y; h[6] = (_Float16)v1.z; h[7] = (_Float16)v1.w;
        *(half8*)(ch + (size_t)c * DD + lane * 8) = h;
        float s = v0.x*v0.x + v0.y*v0.y + v0.z*v0.z + v0.w*v0.w
                + v1.x*v1.x + v1.y*v1.y + v1.z*v1.z + v1.w*v1.w;
        #pragma unroll
        for (int off = 32; off > 0; off >>= 1) s += __shfl_down(s, off, 64);
        if (lane == 0) csq[c] = s - 448.0f;          // Sterbenz-exact recentre
        if (cb == 0)
            for (int i = threadIdx.x; i < FCAP; i += 256) rlist[i] = 0;
    }
}

// ---------------- coarse fp16 MFMA distance, 128 rows x 512 cols ------------
// Carried top2 = packed keys (2 x 16 uints); butterfly once per block.
__global__ __launch_bounds__(256) void dist_f16(const _Float16* __restrict__ xh,
                                                const _Float16* __restrict__ ch,
                                                const float* __restrict__ csq,
                                                unsigned* __restrict__ pk1,
                                                unsigned* __restrict__ pk2) {
    __shared__ __align__(16) _Float16 ash[128 * 32];
    __shared__ __align__(16) _Float16 bsh[128 * 32];

    const int tid = threadIdx.x;
    const int w = tid >> 6, lane = tid & 63;
    const int wr = w >> 1, wc = w & 1;
    const int quad = lane >> 4, u = lane & 15;
    const int rowBase = blockIdx.x * 128;
    const int chunkBase = blockIdx.y * 512;

    unsigned kb[16], ks[16];
    #pragma unroll
    for (int t = 0; t < 16; t++) { kb[t] = 0xFFFFFFFFu; ks[t] = 0xFFFFFFFFu; }

    for (int ct = 0; ct < 4; ct++) {
        const int colBase = chunkBase + ct * 128;
        f32x4 acc[4][4] = {};

        for (int kc = 0; kc < DD / 32; kc++) {
            __syncthreads();
            #pragma unroll
            for (int i = 0; i < 2; i++) {
                int g = 128 * w + 64 * i + lane;       // granule 0..511 (16B each)
                int r = g >> 2, hh = g & 3;
                const _Float16* gA = xh + (size_t)(rowBase + r) * DD + kc * 32 + hh * 8;
                const _Float16* gB = ch + (size_t)(colBase + r) * DD + kc * 32 + hh * 8;
                __builtin_amdgcn_global_load_lds(
                    (const __attribute__((address_space(1))) void*)gA,
                    (__attribute__((address_space(3))) void*)(ash + g * 8), 16, 0, 0);
                __builtin_amdgcn_global_load_lds(
                    (const __attribute__((address_space(1))) void*)gB,
                    (__attribute__((address_space(3))) void*)(bsh + g * 8), 16, 0, 0);
            }
            __syncthreads();

            half8 af[4], bf[4];
            #pragma unroll
            for (int f = 0; f < 4; f++) {
                af[f] = *(const half8*)(ash + (wr * 64 + f * 16 + u) * 32 + quad * 8);
                bf[f] = *(const half8*)(bsh + (wc * 64 + f * 16 + u) * 32 + quad * 8);
            }
            #pragma unroll
            for (int fr = 0; fr < 4; fr++)
                #pragma unroll
                for (int fc = 0; fc < 4; fc++)
                    acc[fr][fc] = __builtin_amdgcn_mfma_f32_16x16x32_f16(af[fr], bf[fc], acc[fr][fc], 0, 0, 0);
        }

        // fold 64 values/thread into packed top2 (3-op branchless update)
        #pragma unroll
        for (int fc = 0; fc < 4; fc++) {
            int col = colBase + wc * 64 + fc * 16 + u;
            float cq = csq[col];
            unsigned ckey = (unsigned)col;             // < 2048 -> 11 bits
            #pragma unroll
            for (int fr = 0; fr < 4; fr++) {
                #pragma unroll
                for (int reg = 0; reg < 4; reg++) {
                    int t = fr * 4 + reg;
                    float v = fmaf(-2.0f, acc[fr][fc][reg], cq);
                    unsigned k = (sortable(v) & 0xFFFFF800u) | ckey;
                    unsigned mn = min(kb[t], k);
                    ks[t] = min(ks[t], max(kb[t], k));
                    kb[t] = mn;
                }
            }
        }
    }

    // butterfly across the 16 u-lanes, once per block
    const int cbi = blockIdx.y * 2 + wc;               // 0..7 partials
    #pragma unroll
    for (int fr = 0; fr < 4; fr++) {
        #pragma unroll
        for (int reg = 0; reg < 4; reg++) {
            int t = fr * 4 + reg;
            unsigned b = kb[t], s = ks[t];
            #pragma unroll
            for (int m = 1; m < 16; m <<= 1) {
                unsigned ob = __shfl_xor(b, m, 64);
                unsigned os = __shfl_xor(s, m, 64);
                unsigned mn = min(b, ob);
                s = min(min(s, os), max(b, ob));
                b = mn;
            }
            if (u == 0) {
                int grow = rowBase + wr * 64 + fr * 16 + quad * 4 + reg;
                pk1[cbi * BROWS + grow] = b;
                pk2[cbi * BROWS + grow] = s;
            }
        }
    }
}

// -------- fused: merge 8 partials/row -> label + flag + gather assigned -----
__global__ __launch_bounds__(256) void reduce_gather(const unsigned* __restrict__ pk1,
                                                     const unsigned* __restrict__ pk2,
                                                     const float* __restrict__ cen,
                                                     float* __restrict__ out,
                                                     int* __restrict__ rlist,
                                                     int* __restrict__ ctr) {
    __shared__ int lab[256];
    const int tid = threadIdx.x;
    const int rowBase = blockIdx.x * 256;      // grid 128
    const int row = rowBase + tid;

    unsigned kb = 0xFFFFFFFFu, ks = 0xFFFFFFFFu;
    #pragma unroll
    for (int p = 0; p < 8; p++) {
        unsigned k1 = pk1[p * BROWS + row];
        unsigned k2 = pk2[p * BROWS + row];
        unsigned mn = min(kb, k1);
        ks = min(min(ks, k2), max(kb, k1));
        kb = mn;
    }
    int bi = (int)(kb & 2047u);
    out[row] = (float)bi;
    lab[tid] = bi;
    float gap = unsortable(ks & 0xFFFFF800u) - unsortable(kb & 0xFFFFF800u);
    if (gap < TAUP) {
        int slot = atomicAdd(ctr, 1);
        if (slot < FCAP) rlist[slot] = row;
    }
    __syncthreads();

    float* assigned = out + BROWS;
    #pragma unroll 4
    for (int it = 0; it < 128; it++) {         // 256 rows x 128 float4
        int s2 = it * 256 + tid;
        int r  = s2 >> 7;                      // row in block 0..255
        int f  = (s2 & 127) * 4;
        float4 v = *(const float4*)(cen + (size_t)lab[r] * DD + f);
        *(float4*)(assigned + (size_t)(rowBase + r) * DD + f) = v;
    }
}

// ---------------- exact fp32 rescore of flagged rows, 32 rows x 128 cols ----
__global__ __launch_bounds__(256, 2) void fixup_dist(const float* __restrict__ x,
                                                     const float* __restrict__ cen,
                                                     const float* __restrict__ csq,
                                                     const int* __restrict__ rlist,
                                                     const int* __restrict__ ctr,
                                                     float* __restrict__ fbest,
                                                     int*   __restrict__ fidx) {
    int n = min(*ctr, FCAP);
    int tilebase = blockIdx.y * 32;
    if (tilebase >= n) return;

    __shared__ float xs[16][36];
    __shared__ float cs[16][132];
    __shared__ float redv[32][33];
    __shared__ int   redi[32][33];
    __shared__ int   rows[32];

    const int tid = threadIdx.x;
    if (tid < 32) rows[tid] = rlist[tilebase + tid];
    __syncthreads();

    const int ty = tid >> 5, tx = tid & 31;    // ty 0..7 (4 rows), tx 0..31 (4 cols)
    const int colBase = blockIdx.x * 128;

    float acc[4][4] = {};
    for (int dk = 0; dk < DD; dk += 16) {
        if (tid < 128) {                        // x tile: 32 rows x 16 k
            int r  = tid >> 2;
            int dc = (tid & 3) * 4;
            float4 xv = *(const float4*)(x + (size_t)rows[r] * DD + dk + dc);
            xs[dc + 0][r] = xv.x + EPS; xs[dc + 1][r] = xv.y + EPS;
            xs[dc + 2][r] = xv.z + EPS; xs[dc + 3][r] = xv.w + EPS;
        }
        #pragma unroll
        for (int sI = 0; sI < 2; sI++) {        // c tile: 128 cols x 16 k
            int id = tid + sI * 256;
            int r  = id >> 2;
            int dc = (id & 3) * 4;
            float4 cv = *(const float4*)(cen + (size_t)(colBase + r) * DD + dk + dc);
            cs[dc + 0][r] = cv.x; cs[dc + 1][r] = cv.y;
            cs[dc + 2][r] = cv.z; cs[dc + 3][r] = cv.w;
        }
        __syncthreads();
        #pragma unroll
        for (int k = 0; k < 16; k++) {
            float4 a0 = *(const float4*)&xs[k][ty * 4];
            float4 b0 = *(const float4*)&cs[k][tx * 4];
            float a[4] = {a0.x, a0.y, a0.z, a0.w};
            float b[4] = {b0.x, b0.y, b0.z, b0.w};
            #pragma unroll
            for (int i = 0; i < 4; i++)
                #pragma unroll
                for (int j = 0; j < 4; j++)
                    acc[i][j] += a[i] * b[j];
        }
        __syncthreads();
    }

    float bv[4]; int bixv[4];
    #pragma unroll
    for (int i = 0; i < 4; i++) { bv[i] = 3.4e38f; bixv[i] = 0x7fffffff; }
    #pragma unroll
    for (int j = 0; j < 4; j++) {
        int col = colBase + tx * 4 + j;
        float cq = csq[col];
        #pragma unroll
        for (int i = 0; i < 4; i++) {
            float v = cq - 2.0f * acc[i][j];
            if (v < bv[i] || (v == bv[i] && col < bixv[i])) { bv[i] = v; bixv[i] = col; }
        }
    }
    #pragma unroll
    for (int i = 0; i < 4; i++) {
        redv[ty * 4 + i][tx] = bv[i];
        redi[ty * 4 + i][tx] = bixv[i];
    }
    __syncthreads();
    if (tid < 32) {
        float b = 3.4e38f; int bi = 0x7fffffff;
        #pragma unroll
        for (int t = 0; t < 32; t++) {
            float v = redv[tid][t]; int ix = redi[tid][t];
            if (v < b || (v == b && ix < bi)) { b = v; bi = ix; }
        }
        fbest[blockIdx.x * FCAP + tilebase + tid] = b;
        fidx [blockIdx.x * FCAP + tilebase + tid] = bi;
    }
}

// -------- fused: final reduce over 16 col-chunks + re-gather flagged rows ---
__global__ __launch_bounds__(256) void fixup_final(const float* __restrict__ fbest,
                                                   const int* __restrict__ fidx,
                                                   const int* __restrict__ rlist,
                                                   const int* __restrict__ ctr,
                                                   const float* __restrict__ cen,
                                                   float* __restrict__ out) {
    int n = min(*ctr, FCAP);
    int base = blockIdx.x * 4;                  // grid FCAP/4 = 1024, early-exit
    if (base >= n) return;

    __shared__ int lab4[4];
    __shared__ int rows4[4];
    const int tid = threadIdx.x;

    if (tid < 4) {
        int sI = base + tid;
        if (sI < n) {
            float b = 3.4e38f; int bi = 0x7fffffff;
            #pragma unroll
            for (int c = 0; c < 16; c++) {
                float v = fbest[c * FCAP + sI]; int ix = fidx[c * FCAP + sI];
                if (v < b || (v == b && ix < bi)) { b = v; bi = ix; }
            }
            int row = rlist[sI];
            out[row] = (float)bi;
            rows4[tid] = row; lab4[tid] = bi;
        } else {
            rows4[tid] = -1;
        }
    }
    __syncthreads();

    float* assigned = out + BROWS;
    #pragma unroll
    for (int it = 0; it < 2; it++) {            // 4 rows x 128 float4
        int s2 = it * 256 + tid;
        int rr = s2 >> 7;
        int f  = (s2 & 127) * 4;
        if (rows4[rr] >= 0) {
            float4 v = *(const float4*)(cen + (size_t)lab4[rr] * DD + f);
            *(float4*)(assigned + (size_t)rows4[rr] * DD + f) = v;
        }
    }
}

extern "C" void kernel_launch(void* const* d_in, const int* in_sizes, int n_in,
                              void* d_out, int out_size, void* d_ws, size_t ws_size,
                              hipStream_t stream) {
    const float* x   = (const float*)d_in[0];
    const float* cen = (const float*)d_in[1];

    char* base = (char*)d_ws;
    _Float16* xh   = (_Float16*)(base);                    // 32 MB
    _Float16* ch   = (_Float16*)(base + 33554432);         // 2 MB
    float* csq     = (float*)(base + 35651584);            // 8 KB
    unsigned* pk1  = (unsigned*)(base + 35659776);         // 1 MB (8 partials)
    unsigned* pk2  = (unsigned*)(base + 36708352);         // 1 MB
    int*   rlist   = (int*)  (base + 37756928);            // 16 KB
    float* fbest   = (float*)(base + 37773312);            // 256 KB
    int*   fidx    = (int*)  (base + 38035456);            // 256 KB
    int*   ctr     = (int*)  (base + 38297600);            // 4 B

    prep<<<8192 + 512, 256, 0, stream>>>(x, cen, xh, ch, csq, rlist, ctr);
    dist_f16<<<dim3(BROWS / 128, KC / 512), 256, 0, stream>>>(xh, ch, csq, pk1, pk2);
    reduce_gather<<<BROWS / 256, 256, 0, stream>>>(pk1, pk2, cen, (float*)d_out, rlist, ctr);
    fixup_dist<<<dim3(KC / 128, FCAP / 32), 256, 0, stream>>>(x, cen, csq, rlist, ctr, fbest, fidx);
    fixup_final<<<FCAP / 4, 256, 0, stream>>>(fbest, fidx, rlist, ctr, cen, (float*)d_out);
}